// Round 10
// baseline (69.136 us; speedup 1.0000x reference)
//
#include <hip/hip_runtime.h>
#include <math.h>

#define WIN 16   // +/- phoneme-index window (rounds 1/5/6/8 verified)
#define FPW 8    // frames per wave
#define NW  4    // waves per block
#define FPB (FPW * NW)   // 32 frames per block
#define CH  8    // staged rows per chunk
#define NBUF 3   // triple-buffered rows (depth-2 prefetch)

#define AS1 __attribute__((address_space(1)))
#define AS3 __attribute__((address_space(3)))

// Kernel 1: per-batch inclusive cumsum of durations (double precision scan),
// centers c[b,n] = cumsum(dur)[b,n] - 0.5*dur[b,n]   (verbatim)
__global__ void centers_kernel(const float* __restrict__ dur,
                               float* __restrict__ c, int N) {
    extern __shared__ double s[];
    int b = blockIdx.x;
    int n = threadIdx.x;
    float d = (n < N) ? dur[(size_t)b * N + n] : 0.0f;
    if (n < N) s[n] = (double)d;
    __syncthreads();
    for (int off = 1; off < N; off <<= 1) {
        double v = (n >= off && n < N) ? s[n - off] : 0.0;
        __syncthreads();
        if (n < N) s[n] += v;
        __syncthreads();
    }
    if (n < N) c[(size_t)b * N + n] = (float)(s[n] - 0.5 * (double)d);
}

// Kernel 2: block = 4 waves x 8 frames. Round-8 math verbatim (ballot
// search, per-frame softmax, full-wave shfl gather, LDS-table broadcast,
// ascending-k fma => bit-identical output). New: triple-buffered CH=8
// chunks with depth-2 async prefetch and counted s_waitcnt vmcnt(4) +
// raw s_barrier — prefetch stays in flight across barriers (never drain
// to 0 mid-loop); first 2 chunks' DMA overlaps the softmax prologue.
__global__ __launch_bounds__(256, 3) void upsample_pipe(
    const float* __restrict__ x,    // [B,N,H]
    const int* __restrict__ lens,   // [B]
    const float* __restrict__ c,    // [B,N]
    float* __restrict__ out,        // [B,T,H]
    int B, int N, int H, int T) {
    __shared__ float rows[NBUF][CH][512];  // 48 KB staged input rows (H=512)
    __shared__ float tbl[NW][CH * FPW];    // per-wave weights: 8 per k (1 KB)
    __shared__ int   bnd[2];               // block union window [n0, nEnd]

    int nwg = gridDim.x;
    int bid = blockIdx.x;
    if ((nwg & 7) == 0) {                  // XCD-bijective swizzle
        int cpx = nwg >> 3;
        bid = (bid & 7) * cpx + (bid >> 3);
    }
    int wave = threadIdx.x >> 6;
    int lane = threadIdx.x & 63;

    int tilesPerB = T / FPB;
    int b   = bid / tilesPerB;
    int t0b = (bid - b * tilesPerB) * FPB;
    int t0  = t0b + wave * FPW;            // this wave's first frame

    const float* cb = c + (size_t)b * N;
    int L = lens[b];
    if (L < 1) L = 1;
    if (L > N) L = N;

    float tf[FPW];
    #pragma unroll
    for (int f = 0; f < FPW; ++f) tf[f] = (float)(t0 + f);

    // ---- one ballot lower_bound pass serves all 8 frames ----
    int lo[FPW];
    #pragma unroll
    for (int f = 0; f < FPW; ++f) lo[f] = 0;
    for (int s = 0; s < N; s += 64) {
        int n = s + lane;
        float v = (n < N) ? cb[n] : 3.0e38f;
        bool inb = (n < L);
        #pragma unroll
        for (int f = 0; f < FPW; ++f)
            lo[f] += __popcll(__ballot(inb && (v < tf[f])));
    }

    // ---- windows only (cheap; softmax deferred until DMA is in flight) ----
    int a[FPW], e[FPW];
    #pragma unroll
    for (int f = 0; f < FPW; ++f) {
        int j = lo[f];
        if (j >= L) j = L - 1;
        float cj   = cb[j];
        float cjm1 = cb[(j > 0) ? (j - 1) : 0];
        if (j > 0 && (tf[f] - cjm1) < (cj - tf[f])) j--;
        int af = j - WIN; if (af < 0) af = 0;
        int ef = j + WIN; if (ef > L - 1) ef = L - 1;
        a[f] = af; e[f] = ef;
    }

    // block union window: nearest-index monotone in t => [w0.a[0], w3.e[7]]
    if (wave == 0 && lane == 0) bnd[0] = a[0];
    if (wave == NW - 1 && lane == 0) bnd[1] = e[FPW - 1];
    __syncthreads();
    int n0   = bnd[0];
    int span = bnd[1] - n0 + 1;
    int nchunks = (span + CH - 1) / CH;

    const float* gbase = x + ((size_t)b * N + n0) * (size_t)H;

    // async stage: ALWAYS 4 DMA insts/wave (tail rows clamp to span-1 into
    // unused slots) so the counted vmcnt is exact. Linear dest == linear read.
    auto stage = [&](int cidx) {
        int kb  = cidx * CH;
        int buf = cidx % NBUF;
        #pragma unroll
        for (int r0 = 0; r0 < CH; r0 += NW) {
            int r  = r0 + wave;
            int rr = kb + r; if (rr > span - 1) rr = span - 1;
            const char* g = (const char*)(gbase + (size_t)rr * H);
            __builtin_amdgcn_global_load_lds(
                (const AS1 void*)(g + lane * 16),
                (AS3 void*)&rows[buf][r][0], 16, 0, 0);
            __builtin_amdgcn_global_load_lds(
                (const AS1 void*)(g + 1024 + lane * 16),
                (AS3 void*)&rows[buf][r][256], 16, 0, 0);
        }
    };

    stage(0);
    if (nchunks > 1) stage(1);

    // ---- per-frame softmax (verbatim numerics; overlaps the DMA) ----
    float w[FPW];
    #pragma unroll
    for (int f = 0; f < FPW; ++f) {
        int K = e[f] - a[f] + 1;
        float sc = -3.0e38f;
        if (lane < K) {
            float d = tf[f] - cb[a[f] + lane];
            sc = -0.5f * d * d;
        }
        float m = sc;
        #pragma unroll
        for (int off = 32; off; off >>= 1) m = fmaxf(m, __shfl_xor(m, off));
        float ev = (lane < K) ? __expf(sc - m) : 0.0f;
        float sum = ev;
        #pragma unroll
        for (int off = 32; off; off >>= 1) sum += __shfl_xor(sum, off);
        w[f] = ev / sum;                   // lanes >= K hold exactly 0.0f
    }

    float4 acc[FPW][2];
    #pragma unroll
    for (int f = 0; f < FPW; ++f) {
        acc[f][0] = make_float4(0.f, 0.f, 0.f, 0.f);
        acc[f][1] = make_float4(0.f, 0.f, 0.f, 0.f);
    }

    for (int cidx = 0; cidx < nchunks; ++cidx) {
        int kb = cidx * CH;
        int klen = span - kb; if (klen > CH) klen = CH;
        int buf = cidx % NBUF;

        // chunk c resident; chunk c+1's 4 loads may stay in flight
        if (cidx == nchunks - 1)
            asm volatile("s_waitcnt vmcnt(0)" ::: "memory");
        else
            asm volatile("s_waitcnt vmcnt(4)" ::: "memory");
        __builtin_amdgcn_s_barrier();

        // depth-2 prefetch; dest buffer's last reader finished pre-barrier
        if (cidx + 2 < nchunks) stage(cidx + 2);

        // per-wave weight table (full-wave shfls, verbatim round-8; only
        // the tbl write is predicated). Same-wave LDS write->read ordering
        // is handled by compiler lgkmcnt.
        int nn = kb + lane;
        float wv[FPW];
        #pragma unroll
        for (int f = 0; f < FPW; ++f) {
            unsigned q = (unsigned)(nn + n0 - a[f]);
            float g = __shfl(w[f], (int)(q & 63u));
            wv[f] = (q < 64u) ? g : 0.0f;
        }
        if (lane < klen) {
            float4* tw = (float4*)&tbl[wave][lane * FPW];
            tw[0] = make_float4(wv[0], wv[1], wv[2], wv[3]);
            tw[1] = make_float4(wv[4], wv[5], wv[6], wv[7]);
        }

        // fma from LDS, ascending k (bit-identical accumulation)
        for (int k = 0; k < klen; ++k) {
            const float4* twk = (const float4*)&tbl[wave][k * FPW];  // broadcast
            float4 wlo = twk[0], whi = twk[1];
            const float4* row = (const float4*)rows[buf][k];
            float4 va = row[lane];
            float4 vb = row[64 + lane];
            const float wk[FPW] = { wlo.x, wlo.y, wlo.z, wlo.w,
                                    whi.x, whi.y, whi.z, whi.w };
            #pragma unroll
            for (int f = 0; f < FPW; ++f) {
                acc[f][0].x = fmaf(wk[f], va.x, acc[f][0].x);
                acc[f][0].y = fmaf(wk[f], va.y, acc[f][0].y);
                acc[f][0].z = fmaf(wk[f], va.z, acc[f][0].z);
                acc[f][0].w = fmaf(wk[f], va.w, acc[f][0].w);
                acc[f][1].x = fmaf(wk[f], vb.x, acc[f][1].x);
                acc[f][1].y = fmaf(wk[f], vb.y, acc[f][1].y);
                acc[f][1].z = fmaf(wk[f], vb.z, acc[f][1].z);
                acc[f][1].w = fmaf(wk[f], vb.w, acc[f][1].w);
            }
        }
        // no trailing barrier: next iteration's waitcnt+barrier handles
        // both residency and buffer-reuse safety (NBUF=3)
    }

    // ---- store the wave's 8 frames ----
    float* obase = out + ((size_t)b * T + t0) * (size_t)H;
    #pragma unroll
    for (int f = 0; f < FPW; ++f) {
        float4* o = (float4*)(obase + (size_t)f * H);
        o[lane]      = acc[f][0];
        o[64 + lane] = acc[f][1];
    }
}

extern "C" void kernel_launch(void* const* d_in, const int* in_sizes, int n_in,
                              void* d_out, int out_size, void* d_ws, size_t ws_size,
                              hipStream_t stream) {
    const float* x    = (const float*)d_in[0];  // [B,N,H] f32
    const int*   lens = (const int*)d_in[1];    // [B] int
    const float* dur  = (const float*)d_in[2];  // [B,N] f32

    int B  = in_sizes[1];
    int BN = in_sizes[2];
    int N  = BN / B;
    int H  = in_sizes[0] / BN;
    int T  = out_size / (B * H);

    float* c = (float*)d_ws;  // B*N floats

    centers_kernel<<<B, N, N * sizeof(double), stream>>>(dur, c, N);

    int blocks = (B * T) / FPB;             // 32 frames per block
    upsample_pipe<<<blocks, 256, 0, stream>>>(x, lens, c, (float*)d_out,
                                              B, N, H, T);
}

// Round 11
// 64.552 us; speedup vs baseline: 1.0710x; 1.0710x over previous
//
#include <hip/hip_runtime.h>
#include <math.h>

#define WIN 16   // +/- phoneme-index window (rounds 1/5/6/8 verified)
#define FPW 8    // frames per wave
#define NW  4    // waves per block (independent; no block-level sync)
#define FPB (FPW * NW)   // 32 frames per block
#define CHK 64   // weight-table chunk (covers K<=33 window offsets)

// Kernel 1: per-batch inclusive cumsum of durations (double precision scan),
// centers c[b,n] = cumsum(dur)[b,n] - 0.5*dur[b,n]   (verbatim)
__global__ void centers_kernel(const float* __restrict__ dur,
                               float* __restrict__ c, int N) {
    extern __shared__ double s[];
    int b = blockIdx.x;
    int n = threadIdx.x;
    float d = (n < N) ? dur[(size_t)b * N + n] : 0.0f;
    if (n < N) s[n] = (double)d;
    __syncthreads();
    for (int off = 1; off < N; off <<= 1) {
        double v = (n >= off && n < N) ? s[n - off] : 0.0;
        __syncthreads();
        if (n < N) s[n] += v;
        __syncthreads();
    }
    if (n < N) c[(size_t)b * N + n] = (float)(s[n] - 0.5 * (double)d);
}

// Kernel 2: 4 independent waves per block, 8 frames per wave. X is L2-resident
// (16.7 MB; ~2 MB/XCD with the swizzle) => rows read DIRECTLY from global (no
// LDS staging, no barriers, no DMA). Round-8 math verbatim except the window
// max is computed directly as the nearest-center score (bit-identical: it IS
// the max of the windowed scores, same expression & rounding), replacing the
// 6-shfl fmax reduction. Depth-2 manual load pipeline hides L2 latency.
__global__ __launch_bounds__(256, 3) void upsample_direct(
    const float* __restrict__ x,    // [B,N,H]
    const int* __restrict__ lens,   // [B]
    const float* __restrict__ c,    // [B,N]
    float* __restrict__ out,        // [B,T,H]
    int B, int N, int H, int T) {
    __shared__ float tbl[NW][CHK * FPW];   // per-wave weights: 8 per k (8 KB)

    int nwg = gridDim.x;
    int bid = blockIdx.x;
    if ((nwg & 7) == 0) {                  // XCD-bijective swizzle
        int cpx = nwg >> 3;
        bid = (bid & 7) * cpx + (bid >> 3);
    }
    int wave = threadIdx.x >> 6;
    int lane = threadIdx.x & 63;

    int tilesPerB = T / FPB;
    int b  = bid / tilesPerB;
    int t0 = (bid - b * tilesPerB) * FPB + wave * FPW;

    const float* cb = c + (size_t)b * N;
    int L = lens[b];
    if (L < 1) L = 1;
    if (L > N) L = N;

    float tf[FPW];
    #pragma unroll
    for (int f = 0; f < FPW; ++f) tf[f] = (float)(t0 + f);

    // ---- one ballot lower_bound pass serves all 8 frames (verbatim) ----
    int lo[FPW];
    #pragma unroll
    for (int f = 0; f < FPW; ++f) lo[f] = 0;
    for (int s = 0; s < N; s += 64) {
        int n = s + lane;
        float v = (n < N) ? cb[n] : 3.0e38f;
        bool inb = (n < L);
        #pragma unroll
        for (int f = 0; f < FPW; ++f)
            lo[f] += __popcll(__ballot(inb && (v < tf[f])));
    }

    // ---- windows + direct max (== nearest-center score, bit-identical) ----
    int a[FPW], e[FPW];
    float m_[FPW];
    #pragma unroll
    for (int f = 0; f < FPW; ++f) {
        int j = lo[f];
        if (j >= L) j = L - 1;
        float cj   = cb[j];
        float cjm1 = cb[(j > 0) ? (j - 1) : 0];
        float csel = cj;
        if (j > 0 && (tf[f] - cjm1) < (cj - tf[f])) { j--; csel = cjm1; }
        int af = j - WIN; if (af < 0) af = 0;
        int ef = j + WIN; if (ef > L - 1) ef = L - 1;
        a[f] = af; e[f] = ef;
        float dm = tf[f] - csel;
        m_[f] = -0.5f * dm * dm;           // max of windowed scores
    }

    // ---- per-frame softmax (sum-reduce verbatim; lane k holds w_k) ----
    float w[FPW];
    #pragma unroll
    for (int f = 0; f < FPW; ++f) {
        int K = e[f] - a[f] + 1;
        float ev = 0.0f;
        if (lane < K) {
            float d  = tf[f] - cb[a[f] + lane];
            float sc = -0.5f * d * d;
            ev = __expf(sc - m_[f]);
        }
        float sum = ev;
        #pragma unroll
        for (int off = 32; off; off >>= 1) sum += __shfl_xor(sum, off);
        w[f] = ev / sum;                   // lanes >= K hold exactly 0.0f
    }

    int n0   = a[0];                       // per-wave union (j monotone)
    int span = e[FPW - 1] - n0 + 1;

    const float4* rbase = (const float4*)(x + ((size_t)b * N + n0) * (size_t)H);
    int H4 = H >> 2;                       // 128

    float4 acc[FPW][2];
    #pragma unroll
    for (int f = 0; f < FPW; ++f) {
        acc[f][0] = make_float4(0.f, 0.f, 0.f, 0.f);
        acc[f][1] = make_float4(0.f, 0.f, 0.f, 0.f);
    }

    for (int kb = 0; kb < span; kb += CHK) {
        int klen = span - kb; if (klen > CHK) klen = CHK;

        // per-wave weight table (full-wave shfls, verbatim round-8; only
        // the tbl write is predicated). Same-wave LDS RAW ordering is
        // handled by compiler-inserted lgkmcnt waits.
        int nn = kb + lane;
        float wv[FPW];
        #pragma unroll
        for (int f = 0; f < FPW; ++f) {
            unsigned q = (unsigned)(nn + n0 - a[f]);
            float g = __shfl(w[f], (int)(q & 63u));
            wv[f] = (q < 64u) ? g : 0.0f;
        }
        if (lane < klen) {
            float4* tw = (float4*)&tbl[wave][lane * FPW];
            tw[0] = make_float4(wv[0], wv[1], wv[2], wv[3]);
            tw[1] = make_float4(wv[4], wv[5], wv[6], wv[7]);
        }

        // ---- depth-2 pipelined direct-from-L2 fma loop (ascending k) ----
        const float4* rp = rbase + (size_t)kb * H4;
        float4 va0, vb0, va1, vb1;
        va0 = rp[lane]; vb0 = rp[64 + lane];
        if (klen > 1) { va1 = rp[H4 + lane]; vb1 = rp[H4 + 64 + lane]; }
        for (int k = 0; k < klen; ++k) {
            float4 na, nb;
            if (k + 2 < klen) {
                const float4* rn = rp + (size_t)(k + 2) * H4;
                na = rn[lane]; nb = rn[64 + lane];
            }
            const float4* twk = (const float4*)&tbl[wave][k * FPW];  // broadcast
            float4 wlo = twk[0], whi = twk[1];
            const float wk[FPW] = { wlo.x, wlo.y, wlo.z, wlo.w,
                                    whi.x, whi.y, whi.z, whi.w };
            #pragma unroll
            for (int f = 0; f < FPW; ++f) {
                acc[f][0].x = fmaf(wk[f], va0.x, acc[f][0].x);
                acc[f][0].y = fmaf(wk[f], va0.y, acc[f][0].y);
                acc[f][0].z = fmaf(wk[f], va0.z, acc[f][0].z);
                acc[f][0].w = fmaf(wk[f], va0.w, acc[f][0].w);
                acc[f][1].x = fmaf(wk[f], vb0.x, acc[f][1].x);
                acc[f][1].y = fmaf(wk[f], vb0.y, acc[f][1].y);
                acc[f][1].z = fmaf(wk[f], vb0.z, acc[f][1].z);
                acc[f][1].w = fmaf(wk[f], vb0.w, acc[f][1].w);
            }
            va0 = va1; vb0 = vb1;
            va1 = na;  vb1 = nb;
        }
    }

    // ---- store the wave's 8 frames ----
    float* obase = out + ((size_t)b * T + t0) * (size_t)H;
    #pragma unroll
    for (int f = 0; f < FPW; ++f) {
        float4* o = (float4*)(obase + (size_t)f * H);
        o[lane]      = acc[f][0];
        o[64 + lane] = acc[f][1];
    }
}

extern "C" void kernel_launch(void* const* d_in, const int* in_sizes, int n_in,
                              void* d_out, int out_size, void* d_ws, size_t ws_size,
                              hipStream_t stream) {
    const float* x    = (const float*)d_in[0];  // [B,N,H] f32
    const int*   lens = (const int*)d_in[1];    // [B] int
    const float* dur  = (const float*)d_in[2];  // [B,N] f32

    int B  = in_sizes[1];
    int BN = in_sizes[2];
    int N  = BN / B;
    int H  = in_sizes[0] / BN;
    int T  = out_size / (B * H);

    float* c = (float*)d_ws;  // B*N floats

    centers_kernel<<<B, N, N * sizeof(double), stream>>>(dur, c, N);

    int blocks = (B * T) / FPB;             // 32 frames per block
    upsample_direct<<<blocks, 256, 0, stream>>>(x, lens, c, (float*)d_out,
                                                B, N, H, T);
}